// Round 5
// baseline (82.680 us; speedup 1.0000x reference)
//
#include <hip/hip_runtime.h>
#include <hip/hip_bf16.h>

// Problem constants (B=4, S=4096, D=1024 from reference)
#define B_DIM 4
#define S_DIM 4096
#define D_DIM 1024
#define M_TOT (B_DIM * S_DIM)      // 16384 rows of flattened [B*S, D]
#define LOOKBACK 64                 // d^64 ~ 3e-10: below fp32 significance
#define CHUNK 128                   // S-rows produced per scan block
#define NT (D_DIM / 64)             // 16 K-tiles of BK=64

typedef unsigned short us;
typedef __attribute__((ext_vector_type(8))) short bf16x8;   // 8 bf16 (4 VGPRs)
typedef __attribute__((ext_vector_type(4))) float f32x4;    // MFMA accumulator
typedef __attribute__((ext_vector_type(4))) unsigned short u16x4;

__device__ __forceinline__ us f2bf(float f) {
  unsigned int u = __builtin_bit_cast(unsigned int, f);
  u += 0x7fffu + ((u >> 16) & 1u);
  return (us)(u >> 16);
}

// ---------------------------------------------------------------------------
// Kernel 1: chunked parallel EMA scan -> causal bf16 in ws.
// ---------------------------------------------------------------------------
__global__ __launch_bounds__(256) void scan_kernel(
    const float* __restrict__ x, const float* __restrict__ dp,
    us* __restrict__ causal) {
  const float dcy = 1.0f / (1.0f + expf(-dp[0]));
  const float omd = 1.0f - dcy;
  const int d0 = blockIdx.x * 512 + threadIdx.x;
  const int s0 = blockIdx.y * CHUNK;
  const size_t base = (size_t)blockIdx.z * S_DIM * D_DIM + d0;
  float st0 = 0.f, st1 = 0.f;
  if (s0 > 0) {
    const float* px = x + base + (size_t)(s0 - LOOKBACK) * D_DIM;
#pragma unroll 8
    for (int i = 0; i < LOOKBACK; ++i) {
      st0 = dcy * st0 + omd * px[0];
      st1 = dcy * st1 + omd * px[256];
      px += D_DIM;
    }
  }
  const float* px = x + base + (size_t)s0 * D_DIM;
  us* pc = causal + base + (size_t)s0 * D_DIM;
#pragma unroll 8
  for (int i = 0; i < CHUNK; ++i) {
    st0 = dcy * st0 + omd * px[0];
    st1 = dcy * st1 + omd * px[256];
    pc[0]   = f2bf(st0);
    pc[256] = f2bf(st1);
    px += D_DIM;
    pc += D_DIM;
  }
}

// ---------------------------------------------------------------------------
// Kernel 2: W fp32 -> bf16
// ---------------------------------------------------------------------------
__global__ __launch_bounds__(256) void convw_kernel(
    const float* __restrict__ W, us* __restrict__ Wb) {
  const int i = (blockIdx.x * 256 + threadIdx.x) * 4;
  const float4 v = *(const float4*)(W + i);
  u16x4 o;
  o.x = f2bf(v.x); o.y = f2bf(v.y); o.z = f2bf(v.z); o.w = f2bf(v.w);
  *(u16x4*)(Wb + i) = o;
}

// ---------------------------------------------------------------------------
// Kernel 3: out = x + causal(bf16) @ Wb(bf16)^T
// Tile 128x64, BK=64, 256 threads (4 waves as 2Mx2N, each 64x32 -> acc = 8
// frags = 32 regs/lane).  Double-buffered LDS (48 KiB -> 3 blocks/CU) with
// the minimum 2-phase schedule: STAGE(t+1); compute(t); one __syncthreads
// per K-step (drain = vmcnt(0) happens once, AFTER compute overlapped the
// staging flight).  XOR LDS swizzle (0 conflicts), bijective XCD swizzle
// with n-major order inside each XCD chunk (concurrent blocks share one
// 256 KB A-band + 2 MB W in the 4 MB XCD L2).
// ---------------------------------------------------------------------------
__global__ __launch_bounds__(256, 3) void gemm_kernel(
    const us* __restrict__ A,   // causal bf16 [M_TOT][D_DIM]
    const us* __restrict__ Bw,  // W bf16 [D_DIM][D_DIM]
    const float* __restrict__ x,
    float* __restrict__ out) {
  __shared__ us As[2][128 * 64];   // 2 x 16 KiB
  __shared__ us Bs[2][64 * 64];    // 2 x 8 KiB

  // nwg = 2048 = 8 * 256 -> bijective chunked remap. Within an XCD chunk,
  // consecutive q share an M-band and sweep N (n-major).
  const int bid = blockIdx.x;
  const int q = bid >> 3;                  // 0..255 within XCD
  const int m0 = (((bid & 7) << 4) + (q >> 4)) * 128;
  const int n0 = (q & 15) * 64;

  const int tid = threadIdx.x;
  const int lane = tid & 63;
  const int wave = tid >> 6;
  const int wr = wave >> 1;       // 0..1 (M half: 64 rows)
  const int wc = wave & 1;        // 0..1 (N half: 32 cols)
  const int lrow = lane & 15;
  const int ls   = lane >> 4;     // 0..3
  const int koff0 = ((0 + ls) ^ (lane & 7)) * 8;
  const int koff1 = ((4 + ls) ^ (lane & 7)) * 8;
  const int arow = (wr * 64 + lrow) * 64;
  const int brow = (wc * 32 + lrow) * 64;

  f32x4 acc[4][2];
#pragma unroll
  for (int i = 0; i < 4; ++i)
#pragma unroll
    for (int j = 0; j < 2; ++j) acc[i][j] = (f32x4)0.f;

  // Stage tile t into buffer p: A 1024 chunks (4/thread), B 512 (2/thread).
  // Linear LDS dest, inverse-swizzled global source (involution (c&7)^(r&7)).
#define STAGE(t, p)                                                            \
  {                                                                            \
    _Pragma("unroll")                                                          \
    for (int it = 0; it < 4; ++it) {                                           \
      const int c = it * 256 + tid;                                            \
      const int r = c >> 3;                                                    \
      const int slot = (c & 7) ^ (r & 7);                                      \
      __builtin_amdgcn_global_load_lds(                                        \
          (const __attribute__((address_space(1))) void*)(A +                  \
              (size_t)(m0 + r) * D_DIM + (t) * 64 + slot * 8),                 \
          (__attribute__((address_space(3))) void*)(&As[p][0] + c * 8),        \
          16, 0, 0);                                                           \
    }                                                                          \
    _Pragma("unroll")                                                          \
    for (int it = 0; it < 2; ++it) {                                           \
      const int c = it * 256 + tid;                                            \
      const int r = c >> 3;                                                    \
      const int slot = (c & 7) ^ (r & 7);                                      \
      __builtin_amdgcn_global_load_lds(                                        \
          (const __attribute__((address_space(1))) void*)(Bw +                 \
              (size_t)(n0 + r) * D_DIM + (t) * 64 + slot * 8),                 \
          (__attribute__((address_space(3))) void*)(&Bs[p][0] + c * 8),        \
          16, 0, 0);                                                           \
    }                                                                          \
  }

  STAGE(0, 0);
  __syncthreads();                  // tile 0 resident

  for (int t = 0; t < NT; ++t) {
    const int p = t & 1;
    if (t + 1 < NT) STAGE(t + 1, p ^ 1);   // prefetch overlaps compute below

#pragma unroll
    for (int ks = 0; ks < 2; ++ks) {
      const int koff = ks ? koff1 : koff0;
      bf16x8 a[4], b[2];
#pragma unroll
      for (int mi = 0; mi < 4; ++mi)
        a[mi] = *(const bf16x8*)(&As[p][0] + arow + mi * 1024 + koff);
#pragma unroll
      for (int nj = 0; nj < 2; ++nj)
        b[nj] = *(const bf16x8*)(&Bs[p][0] + brow + nj * 1024 + koff);
#pragma unroll
      for (int mi = 0; mi < 4; ++mi)
#pragma unroll
        for (int nj = 0; nj < 2; ++nj)
          acc[mi][nj] = __builtin_amdgcn_mfma_f32_16x16x32_bf16(
              a[mi], b[nj], acc[mi][nj], 0, 0, 0);
    }
    __syncthreads();   // single per-iter drain: stage(t+1) landed; readers done
  }

  // ---- epilogue: out = x + acc.  C/D: col = lane&15, row = (lane>>4)*4+r ----
#pragma unroll
  for (int mi = 0; mi < 4; ++mi)
#pragma unroll
    for (int nj = 0; nj < 2; ++nj) {
      const int ocol = n0 + wc * 32 + nj * 16 + lrow;
      const int orow0 = m0 + wr * 64 + mi * 16 + ls * 4;
#pragma unroll
      for (int r = 0; r < 4; ++r) {
        const size_t idx = (size_t)(orow0 + r) * D_DIM + ocol;
        out[idx] = x[idx] + acc[mi][nj][r];
      }
    }
#undef STAGE
}

extern "C" void kernel_launch(void* const* d_in, const int* in_sizes, int n_in,
                              void* d_out, int out_size, void* d_ws, size_t ws_size,
                              hipStream_t stream) {
  const float* x  = (const float*)d_in[0];
  const float* dp = (const float*)d_in[1];
  const float* W  = (const float*)d_in[2];
  float* out = (float*)d_out;

  us* causal = (us*)d_ws;
  us* Wb = (us*)((char*)d_ws + (size_t)M_TOT * D_DIM * 2);

  dim3 g_scan(D_DIM / 512, S_DIM / CHUNK, B_DIM);
  scan_kernel<<<g_scan, 256, 0, stream>>>(x, dp, causal);

  convw_kernel<<<(D_DIM * D_DIM) / (256 * 4), 256, 0, stream>>>(W, Wb);

  gemm_kernel<<<(M_TOT / 128) * (D_DIM / 64), 256, 0, stream>>>(
      causal, Wb, x, out);
}

// Round 6
// 71.933 us; speedup vs baseline: 1.1494x; 1.1494x over previous
//
#include <hip/hip_runtime.h>
#include <hip/hip_bf16.h>

// Problem constants (B=4, S=4096, D=1024 from reference)
#define B_DIM 4
#define S_DIM 4096
#define D_DIM 1024
#define M_TOT (B_DIM * S_DIM)      // 16384 rows of flattened [B*S, D]
#define LOOKBACK 64                 // d^64 ~ 3e-10: below fp32 significance
#define CHUNK 128                   // S-rows produced per scan block
#define NT (D_DIM / 64)             // 16 K-tiles of BK=64

typedef unsigned short us;
typedef __attribute__((ext_vector_type(8))) short bf16x8;   // 8 bf16 (4 VGPRs)
typedef __attribute__((ext_vector_type(4))) float f32x4;    // MFMA accumulator
typedef __attribute__((ext_vector_type(4))) unsigned short u16x4;

__device__ __forceinline__ us f2bf(float f) {
  unsigned int u = __builtin_bit_cast(unsigned int, f);
  u += 0x7fffu + ((u >> 16) & 1u);
  return (us)(u >> 16);
}

// ---------------------------------------------------------------------------
// Kernel 1: chunked parallel EMA scan -> causal bf16 in ws.
// ---------------------------------------------------------------------------
__global__ __launch_bounds__(256) void scan_kernel(
    const float* __restrict__ x, const float* __restrict__ dp,
    us* __restrict__ causal) {
  const float dcy = 1.0f / (1.0f + expf(-dp[0]));
  const float omd = 1.0f - dcy;
  const int d0 = blockIdx.x * 512 + threadIdx.x;
  const int s0 = blockIdx.y * CHUNK;
  const size_t base = (size_t)blockIdx.z * S_DIM * D_DIM + d0;
  float st0 = 0.f, st1 = 0.f;
  if (s0 > 0) {
    const float* px = x + base + (size_t)(s0 - LOOKBACK) * D_DIM;
#pragma unroll 8
    for (int i = 0; i < LOOKBACK; ++i) {
      st0 = dcy * st0 + omd * px[0];
      st1 = dcy * st1 + omd * px[256];
      px += D_DIM;
    }
  }
  const float* px = x + base + (size_t)s0 * D_DIM;
  us* pc = causal + base + (size_t)s0 * D_DIM;
#pragma unroll 8
  for (int i = 0; i < CHUNK; ++i) {
    st0 = dcy * st0 + omd * px[0];
    st1 = dcy * st1 + omd * px[256];
    pc[0]   = f2bf(st0);
    pc[256] = f2bf(st1);
    px += D_DIM;
    pc += D_DIM;
  }
}

// ---------------------------------------------------------------------------
// Kernel 2: W fp32 -> bf16
// ---------------------------------------------------------------------------
__global__ __launch_bounds__(256) void convw_kernel(
    const float* __restrict__ W, us* __restrict__ Wb) {
  const int i = (blockIdx.x * 256 + threadIdx.x) * 4;
  const float4 v = *(const float4*)(W + i);
  u16x4 o;
  o.x = f2bf(v.x); o.y = f2bf(v.y); o.z = f2bf(v.z); o.w = f2bf(v.w);
  *(u16x4*)(Wb + i) = o;
}

// ---------------------------------------------------------------------------
// Kernel 3: out = x + causal(bf16) @ Wb(bf16)^T
// 128x128 tile, BK=64, 4 waves (2Mx2N, wave out 64x64), 64 KiB dbuf LDS ->
// 2 blocks/CU (epilogue of one block overlaps main loop of the other).
// 4 phases per K-tile, one barrier/phase, counted vmcnt(4) once per tile:
//   P0: read a[0..1](4) + b[0..1](4); stage B(t+1)h0 -> other buf; BAR; 8 MFMA
//   P1: read a[2..3](4);              stage B(t+1)h1 -> other buf; BAR; 8 MFMA
//   P2: read b[2..3](4);              stage A(t+2)h0 -> THIS buf;  BAR; 8 MFMA
//   P3:                                stage A(t+2)h1; vmcnt(4); BAR; 8 MFMA
// Queue at P3 wait (2 loads/stage): [A(t+1)x4, B(t+1)x4, A(t+2)x4] -> wait
// oldest 8 (= tile t+1 fully resident), leave A(t+2)'s 4 in flight.
// Stage-safety: stage at phase q touches a region last read at <= q-1; the
// phase-q barrier orders every wave's q-1 reads before any wave's q stage.
// XOR LDS swizzle (0 conflicts), XCD-chunked n-major block swizzle.
// ---------------------------------------------------------------------------
__global__ __launch_bounds__(256, 2) void gemm_kernel(
    const us* __restrict__ A,   // causal bf16 [M_TOT][D_DIM]
    const us* __restrict__ Bw,  // W bf16 [D_DIM][D_DIM]
    const float* __restrict__ x,
    float* __restrict__ out) {
  __shared__ us smem_s[32768];   // 64 KiB: buf p: A at p*16384, B at +8192

  // nwg = 1024 = 8 XCDs x 128. Within an XCD chunk: n-major (8 n-blocks per
  // M-band consecutive) -> concurrent window shares A-bands + W in 4 MB L2.
  const int bid = blockIdx.x;
  const int xcd = bid & 7;
  const int q = bid >> 3;                   // 0..127
  const int m0 = (xcd * 16 + (q >> 3)) * 128;
  const int n0 = (q & 7) * 128;

  const int tid = threadIdx.x;
  const int lane = tid & 63;
  const int wave = tid >> 6;
  const int wr = wave >> 1;       // 0..1 (M half: 64 rows)
  const int wc = wave & 1;        // 0..1 (N half: 64 cols)
  const int lrow = lane & 15;
  const int ls   = lane >> 4;     // 0..3
  const int koff0 = ((0 + ls) ^ (lane & 7)) * 8;
  const int koff1 = ((4 + ls) ^ (lane & 7)) * 8;
  const int arow = (wr * 64 + lrow) * 64;
  const int brow = (wc * 64 + lrow) * 64;

  f32x4 acc[4][4];
#pragma unroll
  for (int i = 0; i < 4; ++i)
#pragma unroll
    for (int j = 0; j < 4; ++j) acc[i][j] = (f32x4)0.f;

  // Stage one half-tile (64 rows x 64 cols bf16 = 8 KB): 2 loads/thread.
  // Linear LDS dest; inverse-swizzled global source (involution (c&7)^(r&7)).
#define STAGE_HALF(SRC, rowbase, t, h, ldsdst)                                 \
  {                                                                            \
    _Pragma("unroll")                                                          \
    for (int it = 0; it < 2; ++it) {                                           \
      const int c = it * 256 + tid;        /* 0..511 */                        \
      const int r = c >> 3;                /* 0..63  */                        \
      const int slot = (c & 7) ^ (r & 7);                                      \
      __builtin_amdgcn_global_load_lds(                                        \
          (const __attribute__((address_space(1))) void*)((SRC) +              \
              (size_t)((rowbase) + (h) * 64 + r) * D_DIM + (t) * 64 + slot * 8),\
          (__attribute__((address_space(3))) void*)((ldsdst) + (h) * 4096 + c * 8),\
          16, 0, 0);                                                           \
    }                                                                          \
  }
#define BAR() __builtin_amdgcn_s_barrier()
#define MFMA_Q(MI0, NJ0)                                                       \
  __builtin_amdgcn_s_setprio(1);                                               \
  _Pragma("unroll")                                                            \
  for (int ks = 0; ks < 2; ++ks)                                               \
    _Pragma("unroll")                                                          \
    for (int mi = 0; mi < 2; ++mi)                                             \
      _Pragma("unroll")                                                        \
      for (int nj = 0; nj < 2; ++nj)                                           \
        acc[(MI0) + mi][(NJ0) + nj] = __builtin_amdgcn_mfma_f32_16x16x32_bf16( \
            a[(MI0) + mi][ks], b[(NJ0) + nj][ks], acc[(MI0) + mi][(NJ0) + nj], \
            0, 0, 0);                                                          \
  __builtin_amdgcn_s_setprio(0)

  us* const A0b = smem_s;            // buf0 A
  us* const B0b = smem_s + 8192;     // buf0 B
  us* const A1b = smem_s + 16384;    // buf1 A

  // ---- prologue: tile0 (A,B halves) + tile1 A halves; wait tile0 only ----
  STAGE_HALF(A,  m0, 0, 0, A0b); STAGE_HALF(A,  m0, 0, 1, A0b);
  STAGE_HALF(Bw, n0, 0, 0, B0b); STAGE_HALF(Bw, n0, 0, 1, B0b);
  STAGE_HALF(A,  m0, 1, 0, A1b); STAGE_HALF(A,  m0, 1, 1, A1b);
  asm volatile("s_waitcnt vmcnt(4)" ::: "memory");  // tile0 resident; A(1) flies
  BAR();

  bf16x8 a[4][2], b[4][2];

  for (int t = 0; t < NT; ++t) {
    const int p = t & 1;
    us* const Ab  = smem_s + p * 16384;
    us* const Bb  = Ab + 8192;
    us* const Bbn = smem_s + (p ^ 1) * 16384 + 8192;

    // ---- P0: a[0..1], b[0..1]; stage B(t+1)h0 ----
#pragma unroll
    for (int mi = 0; mi < 2; ++mi) {
      a[mi][0] = *(const bf16x8*)(Ab + arow + mi * 1024 + koff0);
      a[mi][1] = *(const bf16x8*)(Ab + arow + mi * 1024 + koff1);
    }
#pragma unroll
    for (int nj = 0; nj < 2; ++nj) {
      b[nj][0] = *(const bf16x8*)(Bb + brow + nj * 1024 + koff0);
      b[nj][1] = *(const bf16x8*)(Bb + brow + nj * 1024 + koff1);
    }
    if (t + 1 < NT) STAGE_HALF(Bw, n0, t + 1, 0, Bbn);
    BAR();
    MFMA_Q(0, 0);

    // ---- P1: a[2..3]; stage B(t+1)h1 ----
#pragma unroll
    for (int mi = 2; mi < 4; ++mi) {
      a[mi][0] = *(const bf16x8*)(Ab + arow + mi * 1024 + koff0);
      a[mi][1] = *(const bf16x8*)(Ab + arow + mi * 1024 + koff1);
    }
    if (t + 1 < NT) STAGE_HALF(Bw, n0, t + 1, 1, Bbn);
    BAR();
    MFMA_Q(2, 0);

    // ---- P2: b[2..3]; stage A(t+2)h0 into THIS buf (A dead after P1) ----
#pragma unroll
    for (int nj = 2; nj < 4; ++nj) {
      b[nj][0] = *(const bf16x8*)(Bb + brow + nj * 1024 + koff0);
      b[nj][1] = *(const bf16x8*)(Bb + brow + nj * 1024 + koff1);
    }
    if (t + 2 < NT) STAGE_HALF(A, m0, t + 2, 0, Ab);
    BAR();
    MFMA_Q(0, 2);

    // ---- P3: stage A(t+2)h1; counted tile-end wait; BAR; MFMA ----
    if (t + 2 < NT) STAGE_HALF(A, m0, t + 2, 1, Ab);
    if (t + 2 < NT) {
      asm volatile("s_waitcnt vmcnt(4)" ::: "memory");  // tile t+1 resident
    } else if (t + 1 < NT) {
      asm volatile("s_waitcnt vmcnt(0)" ::: "memory");  // tail drain
    }
    BAR();
    MFMA_Q(2, 2);
  }

  // ---- epilogue: out = x + acc.  C/D: col = lane&15, row = (lane>>4)*4+r ----
#pragma unroll
  for (int mi = 0; mi < 4; ++mi)
#pragma unroll
    for (int nj = 0; nj < 4; ++nj) {
      const int ocol = n0 + wc * 64 + nj * 16 + lrow;
      const int orow0 = m0 + wr * 64 + mi * 16 + ls * 4;
#pragma unroll
      for (int r = 0; r < 4; ++r) {
        const size_t idx = (size_t)(orow0 + r) * D_DIM + ocol;
        out[idx] = x[idx] + acc[mi][nj][r];
      }
    }
#undef STAGE_HALF
#undef BAR
#undef MFMA_Q
}

extern "C" void kernel_launch(void* const* d_in, const int* in_sizes, int n_in,
                              void* d_out, int out_size, void* d_ws, size_t ws_size,
                              hipStream_t stream) {
  const float* x  = (const float*)d_in[0];
  const float* dp = (const float*)d_in[1];
  const float* W  = (const float*)d_in[2];
  float* out = (float*)d_out;

  us* causal = (us*)d_ws;
  us* Wb = (us*)((char*)d_ws + (size_t)M_TOT * D_DIM * 2);

  dim3 g_scan(D_DIM / 512, S_DIM / CHUNK, B_DIM);
  scan_kernel<<<g_scan, 256, 0, stream>>>(x, dp, causal);

  convw_kernel<<<(D_DIM * D_DIM) / (256 * 4), 256, 0, stream>>>(W, Wb);

  gemm_kernel<<<(M_TOT / 128) * (D_DIM / 128), 256, 0, stream>>>(
      causal, Wb, x, out);
}